// Round 1
// baseline (202.562 us; speedup 1.0000x reference)
//
#include <hip/hip_runtime.h>

// Problem constants (from reference)
#define N_NODES   1048576
#define N_GRAPHS  4096
#define NPG       256      // nodes per graph (contiguous batch segments)
#define F_IN      16
#define HID       32

// d_ws layout (floats):
//  [0    .. 511 ] : WzT[c*16+r] = (W_z[0,0]+W_z[1,0])[r][c], r<16
//  [512  .. 1023] : WhT[c*16+r] = (W_h[0,0]+W_h[1,0])[r][c], r<16
//  [1024 .. 1055] : b_z
//  [1056 .. 1087] : b_h
//  [1088 .. 1119] : W_lin
//  [1120]         : b_lin
#define WS_FLOATS 1121

__global__ __launch_bounds__(512) void prep_kernel(
    const float* __restrict__ Wz, const float* __restrict__ bz,
    const float* __restrict__ Wh, const float* __restrict__ bh,
    const float* __restrict__ Wlin, const float* __restrict__ blin,
    float* __restrict__ w)
{
    const int t = threadIdx.x;           // 512 threads, 1 block
    if (t < 512) {
        const int c = t >> 4;            // 0..31
        const int r = t & 15;            // 0..15
        const int src = r * HID + c;     // W[k,0,r,c], k-stride = 48*32 = 1536
        w[t]       = Wz[src] + Wz[1536 + src];
        w[512 + t] = Wh[src] + Wh[1536 + src];
    }
    if (t < HID) {
        w[1024 + t] = bz[t];
        w[1056 + t] = bh[t];
        w[1088 + t] = Wlin[t];
    }
    if (t == 0) w[1120] = blin[0];
}

// Shared per-node math. w points at the layout above (global SGPR path or LDS path).
__device__ __forceinline__ float node_forward(const float xv[F_IN], const float* __restrict__ w)
{
    float acc = 0.0f;
#pragma unroll 4
    for (int c = 0; c < HID; ++c) {
        float az = w[1024 + c];
        float ah = w[1056 + c];
#pragma unroll
        for (int r = 0; r < F_IN; ++r) {
            az = fmaf(xv[r], w[c * 16 + r],        az);
            ah = fmaf(xv[r], w[512 + c * 16 + r],  ah);
        }
        // sigmoid (overflow-safe): exp(-az)->inf => z->0
        const float z  = 1.0f / (1.0f + __expf(-az));
        // tanh (overflow-safe): e->inf => th->1 ; e->0 => th->-1
        const float e  = __expf(2.0f * ah);
        const float th = 1.0f - 2.0f / (e + 1.0f);
        float H = (1.0f - z) * th;
        H = H > 0.0f ? H : 0.0f;               // relu
        acc = fmaf(H, w[1088 + c], acc);       // dot with W_lin
    }
    return acc;
}

__device__ __forceinline__ void reduce_and_store(float acc, const float* w, float* out)
{
    // 256 threads = 4 waves. Wave butterfly then LDS combine.
    const int t = threadIdx.x;
#pragma unroll
    for (int off = 32; off > 0; off >>= 1)
        acc += __shfl_down(acc, off, 64);
    __shared__ float part[4];
    if ((t & 63) == 0) part[t >> 6] = acc;
    __syncthreads();
    if (t == 0) {
        const float s = part[0] + part[1] + part[2] + part[3];
        out[blockIdx.x] = s * (1.0f / (float)NPG) + w[1120];
    }
}

// Main path: weights precomputed in d_ws (wave-uniform global -> s_load -> SGPR operands)
__global__ __launch_bounds__(256) void gcn_main(
    const float* __restrict__ x, const float* __restrict__ w, float* __restrict__ out)
{
    const int node = blockIdx.x * NPG + threadIdx.x;
    const float4* xp = (const float4*)(x + (size_t)node * F_IN);
    const float4 a = xp[0], b = xp[1], c4 = xp[2], d4 = xp[3];
    const float xv[F_IN] = { a.x, a.y, a.z, a.w,  b.x, b.y, b.z, b.w,
                             c4.x, c4.y, c4.z, c4.w,  d4.x, d4.y, d4.z, d4.w };
    const float acc = node_forward(xv, w);
    reduce_and_store(acc, w, out);
}

// Fallback if ws_size is too small: build summed weights in LDS per block.
__global__ __launch_bounds__(256) void gcn_main_lds(
    const float* __restrict__ x,
    const float* __restrict__ Wz, const float* __restrict__ bz,
    const float* __restrict__ Wh, const float* __restrict__ bh,
    const float* __restrict__ Wlin, const float* __restrict__ blin,
    float* __restrict__ out)
{
    __shared__ float w[WS_FLOATS];
    const int t = threadIdx.x;
#pragma unroll
    for (int i = t; i < 512; i += 256) {
        const int c = i >> 4, r = i & 15;
        const int src = r * HID + c;
        w[i]       = Wz[src] + Wz[1536 + src];
        w[512 + i] = Wh[src] + Wh[1536 + src];
    }
    if (t < HID) { w[1024 + t] = bz[t]; w[1056 + t] = bh[t]; w[1088 + t] = Wlin[t]; }
    if (t == 0)  w[1120] = blin[0];
    __syncthreads();

    const int node = blockIdx.x * NPG + t;
    const float4* xp = (const float4*)(x + (size_t)node * F_IN);
    const float4 a = xp[0], b = xp[1], c4 = xp[2], d4 = xp[3];
    const float xv[F_IN] = { a.x, a.y, a.z, a.w,  b.x, b.y, b.z, b.w,
                             c4.x, c4.y, c4.z, c4.w,  d4.x, d4.y, d4.z, d4.w };
    const float acc = node_forward(xv, w);
    reduce_and_store(acc, w, out);
}

extern "C" void kernel_launch(void* const* d_in, const int* in_sizes, int n_in,
                              void* d_out, int out_size, void* d_ws, size_t ws_size,
                              hipStream_t stream)
{
    // setup_inputs order:
    // 0:x 1:edge_index 2:edge_weight 3:batch 4:W_z 5:b_z 6:W_r 7:b_r 8:W_h 9:b_h 10:W_lin 11:b_lin
    const float* x    = (const float*)d_in[0];
    const float* Wz   = (const float*)d_in[4];
    const float* bz   = (const float*)d_in[5];
    const float* Wh   = (const float*)d_in[8];
    const float* bh   = (const float*)d_in[9];
    const float* Wlin = (const float*)d_in[10];
    const float* blin = (const float*)d_in[11];
    float* out = (float*)d_out;

    if (ws_size >= WS_FLOATS * sizeof(float)) {
        float* w = (float*)d_ws;
        prep_kernel<<<1, 512, 0, stream>>>(Wz, bz, Wh, bh, Wlin, blin, w);
        gcn_main<<<N_GRAPHS, NPG, 0, stream>>>(x, w, out);
    } else {
        gcn_main_lds<<<N_GRAPHS, NPG, 0, stream>>>(x, Wz, bz, Wh, bh, Wlin, blin, out);
    }
}